// Round 2
// baseline (1977.237 us; speedup 1.0000x reference)
//
#include <hip/hip_runtime.h>
#include <stdint.h>

#define NTOK 262144
#define DIM 384
#define KC 512

constexpr int MT = 64;            // rows per block
constexpr int DC = 16;            // d-chunk
constexpr int LST = DC + 4;       // LDS row stride = 20 floats: 16B-aligned, staggered banks

// ---------------- Kernel 1: e_sq (bit-exact numpy pairwise_sum replica) ----------------
// numpy: q = emb*emb (per-element rounded, NO fma), then pairwise_sum:
//   384 -> 192+192 -> each 192 -> 96+96; each 96-block: 8 strided accumulators
//   r[j] = sum_{i=0..11} q[i*8+j] (sequential adds), combined
//   ((r0+r1)+(r2+r3)) + ((r4+r5)+(r6+r7)).
// Final: s384 = (s96_0 + s96_1) + (s96_2 + s96_3).
__global__ void esq_kernel(const float* __restrict__ emb, float* __restrict__ ws) {
#pragma clang fp contract(off)
    int k = blockIdx.x * blockDim.x + threadIdx.x;
    if (k == 0) *(double*)(ws + 512) = 0.0;   // loss accumulator at byte offset 2048
    if (k < KC) {
        const float* e = emb + (size_t)k * DIM;
        float s96[4];
        for (int c = 0; c < 4; ++c) {
            const float* p = e + c * 96;
            float r[8];
#pragma unroll
            for (int j = 0; j < 8; ++j) {
                float q = p[j] * p[j];
                r[j] = q;
            }
            for (int i = 8; i < 96; i += 8) {
#pragma unroll
                for (int j = 0; j < 8; ++j) {
                    float q = p[i + j] * p[i + j];
                    r[j] = r[j] + q;
                }
            }
            s96[c] = ((r[0] + r[1]) + (r[2] + r[3])) + ((r[4] + r[5]) + (r[6] + r[7]));
        }
        ws[k] = (s96[0] + s96[1]) + (s96[2] + s96[3]);
    }
}

// ---------------- Kernel 2: fused distances + argmin + gather + loss ----------------
// dot product MUST remain a single sequential fmaf chain over d=0..383 (ascending)
// to bit-match BLAS sgemm's per-element k-sequential FMA accumulation.
__launch_bounds__(256, 2)
__global__ void vq_main(const float* __restrict__ z, const float* __restrict__ emb,
                        const float* __restrict__ ws_esq, double* __restrict__ ws_loss,
                        float* __restrict__ out_zq, float* __restrict__ out_idx) {
    __shared__ float z_lds[MT][LST];
    __shared__ float e_lds[KC][LST];
    __shared__ float esq_lds[KC];
    __shared__ float zsq_part[4][MT];
    __shared__ float zsq_lds[MT];
    __shared__ unsigned long long win_lds[MT];
    __shared__ float loss_part[8];

    const int t   = threadIdx.x;
    const int kid = t & 31;        // 32 k-threads: thread's cols k = kid + 32*j
    const int mid = t >> 5;        // 8 m-groups: thread's rows r = mid*8 + mi
    const int m0  = blockIdx.x * MT;

    esq_lds[t]       = ws_esq[t];
    esq_lds[t + 256] = ws_esq[t + 256];

    float acc[8][16];
#pragma unroll
    for (int a = 0; a < 8; ++a)
#pragma unroll
        for (int b = 0; b < 16; ++b) acc[a][b] = 0.f;

    float zsq_p = 0.f;
    const int sr = t >> 2;          // staging row 0..63
    const int sc = (t & 3) << 2;    // staging col 0,4,8,12

    for (int dc = 0; dc < DIM; dc += DC) {
        __syncthreads();
        // stage z tile [64][16]
        {
            float4 v = *(const float4*)(z + (size_t)(m0 + sr) * DIM + dc + sc);
            *(float4*)&z_lds[sr][sc] = v;
        }
        // stage emb tile [512][16]
#pragma unroll
        for (int i = 0; i < 8; ++i) {
            int k = sr + (i << 6);
            float4 v = *(const float4*)(emb + (size_t)k * DIM + dc + sc);
            *(float4*)&e_lds[k][sc] = v;
        }
        __syncthreads();
        // z_sq partials (any fp32 summation order is argmin-safe: integer-ulp shifts
        // of z_sq commute with the two subsequent roundings within the binade)
        {
            int m = t & 63, q = t >> 6;
#pragma unroll
            for (int dd = 0; dd < 4; ++dd) {
                float v = z_lds[m][q * 4 + dd];
                zsq_p = fmaf(v, v, zsq_p);
            }
        }
        // GEMM inner: 8x16 per-thread outer product over d (d strictly ascending)
#pragma unroll
        for (int d4 = 0; d4 < DC; d4 += 4) {
            float4 a[8];
#pragma unroll
            for (int mi = 0; mi < 8; ++mi)
                a[mi] = *(const float4*)&z_lds[mid * 8 + mi][d4];
#pragma unroll
            for (int j = 0; j < 16; ++j) {
                float4 b = *(const float4*)&e_lds[kid + (j << 5)][d4];
#pragma unroll
                for (int mi = 0; mi < 8; ++mi) {
                    float s = acc[mi][j];
                    s = fmaf(a[mi].x, b.x, s);
                    s = fmaf(a[mi].y, b.y, s);
                    s = fmaf(a[mi].z, b.z, s);
                    s = fmaf(a[mi].w, b.w, s);
                    acc[mi][j] = s;
                }
            }
        }
    }

    // reduce z_sq
    zsq_part[t >> 6][t & 63] = zsq_p;
    __syncthreads();
    if (t < MT)
        zsq_lds[t] = (zsq_part[0][t] + zsq_part[1][t]) + (zsq_part[2][t] + zsq_part[3][t]);
    __syncthreads();

    // argmin per row: d = fl(fl(z_sq - 2*dot) + e_sq), first-index tie-break via packed min
    float row_loss = 0.f;
#pragma unroll
    for (int mi = 0; mi < 8; ++mi) {
        int r = mid * 8 + mi;
        float zs = zsq_lds[r];
        unsigned long long best = ~0ull;
#pragma unroll
        for (int j = 0; j < 16; ++j) {
            int k = kid + (j << 5);
            float t1 = fmaf(-2.f, acc[mi][j], zs);   // == round(zs - 2*dot), 2*dot exact
            float dist = t1 + esq_lds[k];            // second rounding, matches reference
            unsigned long long p =
                ((unsigned long long)__float_as_uint(dist) << 32) | (unsigned)k;
            best = p < best ? p : best;
        }
#pragma unroll
        for (int off = 16; off > 0; off >>= 1) {
            unsigned long long o = __shfl_xor(best, off);
            best = o < best ? o : best;
        }
        if (kid == 0) {
            win_lds[r] = best;
            out_idx[m0 + r] = (float)(unsigned)(best & 0xffffffffu);
            row_loss += __uint_as_float((unsigned)(best >> 32));  // d_min == ||z-e||^2
        }
    }
    if (kid == 0) loss_part[mid] = row_loss;
    __syncthreads();
    if (t == 0) {
        float s = 0.f;
        for (int i = 0; i < 8; ++i) s += loss_part[i];
        atomicAdd(ws_loss, (double)s);
    }

    // gather z_q = emb[best] (emb is L2-resident), coalesced 32-lane row copies
#pragma unroll
    for (int p = 0; p < 8; ++p) {
        int r = (p << 3) + mid;
        unsigned idx = (unsigned)(win_lds[r] & 0xffffffffu);
        const float* er = emb + (size_t)idx * DIM;
        float* orow = out_zq + (size_t)(m0 + r) * DIM;
        for (int c = kid * 4; c < DIM; c += 128)
            *(float4*)(orow + c) = *(const float4*)(er + c);
    }
}

// ---------------- Kernel 3: finalize loss ----------------
__global__ void finalize_kernel(const double* __restrict__ ws_loss, float* __restrict__ out_loss) {
    if (threadIdx.x == 0 && blockIdx.x == 0) {
        double s = *ws_loss;
        *out_loss = (float)(1.25 * s / (double)((size_t)NTOK * DIM));
    }
}

extern "C" void kernel_launch(void* const* d_in, const int* in_sizes, int n_in,
                              void* d_out, int out_size, void* d_ws, size_t ws_size,
                              hipStream_t stream) {
    const float* z   = (const float*)d_in[0];
    const float* emb = (const float*)d_in[1];
    float* out     = (float*)d_out;
    float* ws      = (float*)d_ws;
    float* out_zq  = out;
    float* out_idx = out + (size_t)NTOK * DIM;
    float* out_ls  = out + (size_t)NTOK * DIM + NTOK;

    esq_kernel<<<2, 256, 0, stream>>>(emb, ws);
    vq_main<<<NTOK / MT, 256, 0, stream>>>(z, emb, ws, (double*)(ws + 512), out_zq, out_idx);
    finalize_kernel<<<1, 1, 0, stream>>>((const double*)(ws + 512), out_ls);
}